// Round 7
// baseline (3643.998 us; speedup 1.0000x reference)
//
#include <hip/hip_runtime.h>
#include <climits>

// ---------------------------------------------------------------------------
// GNet: RevIN -> 2-layer GRU (B=128, L=512, H=512, I=96) -> proj -> RevIN^-1
// R7: barrier-free producer/consumer RNN. Per-group (batch-tile, blockIdx%8):
//   cell0: 8 blocks x 4 self-contained waves, NO syncthreads, each wave
//     free-runs h0(t) with per-WAVE monotonic flags; h0 -> 16-slot ring.
//   cell1: 16 blocks (2 LDS pairs), trails cell0 polling its flags (usually
//     already satisfied), syncs only among cell1 via per-BLOCK flags.
// Flags: plain relaxed agent-scope stores (no RMW, no publisher hop);
// waiters poll all flags in ONE round trip (48 lanes + __all).
// Data: relaxed agent atomics (coherence point; no wbl2/inv anywhere).
// Ordering: explicit `s_waitcnt vmcnt(0)` between data stores and flag store.
// R6 post-mortem: participant count / detection path are NOT the bottleneck;
// serialized coherence hops are. This round removes 2 hops and overlaps the
// two cells' chains.
// ---------------------------------------------------------------------------

typedef __attribute__((ext_vector_type(8))) __bf16 bf16x8;
typedef __attribute__((ext_vector_type(4))) float  f32x4;

constexpr int B_  = 128;
constexpr int L_  = 512;
constexpr int H_  = 512;
constexpr int CI_ = 96;
constexpr float EPSR = 1e-5f;
constexpr int RING = 16;            // h0 ring slots (back-pressure t-16)

// ws layout (bytes)
constexpr size_t XN_OFF = 0;                                   // bf16 [L][B][96]
constexpr size_t XN_BYTES = (size_t)L_ * B_ * CI_ * 2;
constexpr size_t YS_OFF = XN_OFF + XN_BYTES;                   // bf16 [L][B][H]
constexpr size_t YS_BYTES = (size_t)L_ * B_ * H_ * 2;
constexpr size_t RING_OFF = YS_OFF + YS_BYTES;                 // bf16 [RING][B][H]
constexpr size_t RING_BYTES = (size_t)RING * B_ * H_ * 2;
constexpr size_t SLOT_BYTES = (size_t)B_ * H_ * 2;
constexpr size_t FLG_OFF = RING_OFF + RING_BYTES;              // 8 grp x 64 u32
constexpr size_t FLG_BYTES = 8 * 64 * 4;
constexpr size_t ST_OFF = FLG_OFF + FLG_BYTES;                 // fp32 stats
constexpr int ST_TM = 0, ST_TSD = 2048, ST_OM = 4096, ST_OSD = 6144,
              ST_CM = 8192, ST_CSD = 16384;

__device__ inline unsigned short f2bf(float f) {
  unsigned u = __builtin_bit_cast(unsigned, f);
  u += 0x7fffu + ((u >> 16) & 1u);
  return (unsigned short)(u >> 16);
}

union U16x8 { uint4 u4; unsigned long long q[2]; unsigned short s[8]; bf16x8 v; };

__device__ inline bf16x8 load_bf8(const unsigned short* p) {   // cached path
  U16x8 t; t.u4 = *(const uint4*)p; return t.v;
}
__device__ inline bf16x8 load_bf8_coh(const unsigned short* p) {
  U16x8 t;
  const unsigned long long* q = (const unsigned long long*)p;
  t.q[0] = __hip_atomic_load(q + 0, __ATOMIC_RELAXED, __HIP_MEMORY_SCOPE_AGENT);
  t.q[1] = __hip_atomic_load(q + 1, __ATOMIC_RELAXED, __HIP_MEMORY_SCOPE_AGENT);
  return t.v;
}
__device__ inline bf16x8 cvt_frag(const float* p) {
  U16x8 t;
  float4 a = *(const float4*)p;
  float4 b = *(const float4*)(p + 4);
  t.s[0] = f2bf(a.x); t.s[1] = f2bf(a.y); t.s[2] = f2bf(a.z); t.s[3] = f2bf(a.w);
  t.s[4] = f2bf(b.x); t.s[5] = f2bf(b.y); t.s[6] = f2bf(b.z); t.s[7] = f2bf(b.w);
  return t.v;
}
__device__ inline f32x4 mfma16(bf16x8 a, bf16x8 b, f32x4 c) {
  return __builtin_amdgcn_mfma_f32_16x16x32_bf16(a, b, c, 0, 0, 0);
}
__device__ inline float sigm(float x) {
  x = fminf(fmaxf(x, -30.f), 30.f);
  return 1.f / (1.f + __expf(-x));
}
__device__ inline float tanh_(float x) {
  x = fminf(fmaxf(x, -15.f), 15.f);
  float e = __expf(-2.f * x);
  return (1.f - e) / (1.f + e);
}
__device__ inline void waitcnt_vm0() { asm volatile("s_waitcnt vmcnt(0)" ::: "memory"); }

// One-round-trip wave-parallel flag poll. fl[0..31]=cell0 per-wave flags,
// fl[32..47]=cell1 per-block flags. lane<32 checks >= tgt0, 32..47 >= tgt1.
__device__ inline void poll_flags(const unsigned* fl, int lane, int tgt0, int tgt1) {
  const unsigned* p = fl + (lane < 48 ? lane : 0);
  const int tgt = (lane < 32) ? tgt0 : tgt1;
  const bool skip = (lane >= 48);
  for (;;) {
    int v = (int)__hip_atomic_load(p, __ATOMIC_RELAXED, __HIP_MEMORY_SCOPE_AGENT);
    if (__all(skip || (v >= tgt))) return;
    __builtin_amdgcn_s_sleep(1);
  }
}

// Pack 4 bf16 gate outputs (rows quad*4+{0..3}, col urow) into 2 u32 coherent
// stores (pair adjacent l16 lanes along the unit dim).
__device__ inline void store_h_packed(unsigned* dst, int m0, int u0, int quad,
                                      int l16, const unsigned us[4]) {
  unsigned sh0 = (unsigned)__shfl_xor((int)us[0], 1);
  unsigned sh1 = (unsigned)__shfl_xor((int)us[1], 1);
  unsigned sh2 = (unsigned)__shfl_xor((int)us[2], 1);
  unsigned sh3 = (unsigned)__shfl_xor((int)us[3], 1);
  bool odd = (l16 & 1) != 0;
  unsigned ownA = odd ? us[2] : us[0], prtA = odd ? sh2 : sh0;
  unsigned ownB = odd ? us[3] : us[1], prtB = odd ? sh3 : sh1;
  unsigned pkA = odd ? ((prtA & 0xffffu) | (ownA << 16))
                     : ((ownA & 0xffffu) | (prtA << 16));
  unsigned pkB = odd ? ((prtB & 0xffffu) | (ownB << 16))
                     : ((ownB & 0xffffu) | (prtB << 16));
  int rA = odd ? 2 : 0;
  size_t idxA = (size_t)(m0 + quad * 4 + rA) * (H_ / 2) + ((u0 + (l16 & ~1)) >> 1);
  __hip_atomic_store(dst + idxA, pkA, __ATOMIC_RELAXED, __HIP_MEMORY_SCOPE_AGENT);
  __hip_atomic_store(dst + idxA + (H_ / 2), pkB, __ATOMIC_RELAXED,
                     __HIP_MEMORY_SCOPE_AGENT);
}

// ---------------------------------------------------------------------------
__global__ void stats_kernel(const float* __restrict__ trt,
                             const float* __restrict__ outh,
                             const float* __restrict__ cov,
                             float* __restrict__ stats) {
  int b = blockIdx.x;
  int ch = threadIdx.x;
  if (ch >= 96) return;
  const float* p; int C; float* mdst; float* sdst; int si;
  if (ch < 16)      { p = trt  + (size_t)b * L_ * 16 + ch;        C = 16; mdst = stats + ST_TM; sdst = stats + ST_TSD; si = b * 16 + ch; }
  else if (ch < 32) { p = outh + (size_t)b * L_ * 16 + (ch - 16); C = 16; mdst = stats + ST_OM; sdst = stats + ST_OSD; si = b * 16 + ch - 16; }
  else              { p = cov  + (size_t)b * L_ * 64 + (ch - 32); C = 64; mdst = stats + ST_CM; sdst = stats + ST_CSD; si = b * 64 + ch - 32; }
  float s = 0.f;
  for (int t = 0; t < L_; ++t) s += p[(size_t)t * C];
  float m = s / (float)L_;
  float q = 0.f;
  for (int t = 0; t < L_; ++t) { float d = p[(size_t)t * C] - m; q += d * d; }
  float sd = sqrtf(q / (float)(L_ - 1));
  mdst[si] = m; sdst[si] = sd;
}

__global__ void norm_kernel(const float* __restrict__ trt,
                            const float* __restrict__ outh,
                            const float* __restrict__ cov,
                            const float* __restrict__ stats,
                            const float* __restrict__ w_t, const float* __restrict__ b_t,
                            const float* __restrict__ w_o, const float* __restrict__ b_o,
                            const float* __restrict__ w_c, const float* __restrict__ b_c,
                            unsigned short* __restrict__ xn) {
  int idx = blockIdx.x * 256 + threadIdx.x;
  int c = idx % CI_;
  int tb = idx / CI_;
  int b = tb % B_;
  int t = tb / B_;
  float v, m, sd, w, bb;
  if (c < 16) {
    v = trt[((size_t)b * L_ + t) * 16 + c];
    m = stats[ST_TM + b * 16 + c]; sd = stats[ST_TSD + b * 16 + c];
    w = w_t[c]; bb = b_t[c];
  } else if (c < 32) {
    int cc = c - 16;
    v = outh[((size_t)b * L_ + t) * 16 + cc];
    m = stats[ST_OM + b * 16 + cc]; sd = stats[ST_OSD + b * 16 + cc];
    w = w_o[cc]; bb = b_o[cc];
  } else {
    int cc = c - 32;
    v = cov[((size_t)b * L_ + t) * 64 + cc];
    m = stats[ST_CM + b * 64 + cc]; sd = stats[ST_CSD + b * 64 + cc];
    w = w_c[cc]; bb = b_c[cc];
  }
  xn[idx] = f2bf((v - m) / (sd + EPSR) * w + bb);
}

// ---------------------------------------------------------------------------
// cell0: one self-contained wave per 16-unit tile; free-running chain.
// step t: poll f0>=t-1 (peers' h0(t-1)) & f1>=t-RING (ring back-pressure);
// h0(t)=cell(x_t, h0(t-1)); store ring slot t%RING; waitcnt; f0[wid]=t;
// then precompute x@Wih0 for t+1 (overlaps peers' latency).
// ---------------------------------------------------------------------------
__device__ __forceinline__ void cell0_run(
    unsigned* fl, int wid, int lane, int u0, int m0,
    const unsigned short* __restrict__ xn, unsigned short* __restrict__ ring,
    const float* __restrict__ WI, const float* __restrict__ WH,
    const float* __restrict__ bi, const float* __restrict__ bh) {
  const int quad = lane >> 4, l16 = lane & 15;
  const int b = m0 + l16, urow = u0 + l16;
  bf16x8 BGI[3][3], BGH[3][16];
#pragma unroll
  for (int g = 0; g < 3; ++g) {
#pragma unroll
    for (int c = 0; c < 3; ++c)
      BGI[g][c] = cvt_frag(WI + (size_t)(g * H_ + urow) * CI_ + 32 * c + quad * 8);
#pragma unroll
    for (int c = 0; c < 16; ++c)
      BGH[g][c] = cvt_frag(WH + (size_t)(g * H_ + urow) * H_ + 32 * c + quad * 8);
  }
  float bi_[3], bh_[3];
#pragma unroll
  for (int g = 0; g < 3; ++g) { bi_[g] = bi[g * H_ + urow]; bh_[g] = bh[g * H_ + urow]; }
  float hp[4] = {0.f, 0.f, 0.f, 0.f};

  // precompute agi for t=1 (x_1 = xn[0])
  f32x4 agi[3];
#pragma unroll
  for (int g = 0; g < 3; ++g) agi[g] = (f32x4){0.f, 0.f, 0.f, 0.f};
  {
    const unsigned short* Agi = xn + (size_t)b * CI_;
#pragma unroll
    for (int c = 0; c < 3; ++c) {
      bf16x8 a = load_bf8(Agi + 32 * c + quad * 8);
      agi[0] = mfma16(a, BGI[0][c], agi[0]);
      agi[1] = mfma16(a, BGI[1][c], agi[1]);
      agi[2] = mfma16(a, BGI[2][c], agi[2]);
    }
  }

  for (int t = 1; t <= 512; ++t) {
    poll_flags(fl, lane, t - 1, t - RING);
    const unsigned short* Agh =
        ring + (size_t)((t - 1) & (RING - 1)) * B_ * H_ + (size_t)b * H_;
    f32x4 agh[3];
#pragma unroll
    for (int g = 0; g < 3; ++g) agh[g] = (f32x4){0.f, 0.f, 0.f, 0.f};
#pragma unroll
    for (int c = 0; c < 16; ++c) {
      bf16x8 a = load_bf8_coh(Agh + 32 * c + quad * 8);
      agh[0] = mfma16(a, BGH[0][c], agh[0]);
      agh[1] = mfma16(a, BGH[1][c], agh[1]);
      agh[2] = mfma16(a, BGH[2][c], agh[2]);
    }
    unsigned us[4];
#pragma unroll
    for (int r = 0; r < 4; ++r) {
      float rr = sigm(agi[0][r] + bi_[0] + agh[0][r] + bh_[0]);
      float zz = sigm(agi[1][r] + bi_[1] + agh[1][r] + bh_[1]);
      float nn = tanh_(agi[2][r] + bi_[2] + rr * (agh[2][r] + bh_[2]));
      float hv = (1.f - zz) * nn + zz * hp[r];
      hp[r] = hv;
      us[r] = f2bf(hv);
    }
    unsigned* dst = (unsigned*)(ring + (size_t)(t & (RING - 1)) * B_ * H_);
    store_h_packed(dst, m0, u0, quad, l16, us);
    waitcnt_vm0();
    __hip_atomic_store(fl + wid, (unsigned)t, __ATOMIC_RELAXED,
                       __HIP_MEMORY_SCOPE_AGENT);
    if (t < 512) {  // precompute agi(t+1) while peers catch up
      const unsigned short* Agi = xn + ((size_t)t * B_ + b) * CI_;
#pragma unroll
      for (int g = 0; g < 3; ++g) agi[g] = (f32x4){0.f, 0.f, 0.f, 0.f};
#pragma unroll
      for (int c = 0; c < 3; ++c) {
        bf16x8 a = load_bf8(Agi + 32 * c + quad * 8);
        agi[0] = mfma16(a, BGI[0][c], agi[0]);
        agi[1] = mfma16(a, BGI[1][c], agi[1]);
        agi[2] = mfma16(a, BGI[2][c], agi[2]);
      }
    }
  }
}

// ---------------------------------------------------------------------------
// cell1 consumer wave: step s: poll f0>=s (h0(s) ready — normally stale);
// gi = h0(s)@Wih1; + gh partial from LDS; h1(s) -> ys[s-1]; f1[blk]=s.
// ---------------------------------------------------------------------------
__device__ __forceinline__ void cell1_cons(
    unsigned* fl, int cblk, int lane, int u0, int m0,
    unsigned short* __restrict__ ys, const unsigned short* __restrict__ ring,
    const float* __restrict__ WI,
    const float* __restrict__ bi, const float* __restrict__ bh,
    float (*exch)[64][4]) {
  const int quad = lane >> 4, l16 = lane & 15;
  const int b = m0 + l16, urow = u0 + l16;
  bf16x8 BGI[3][16];
#pragma unroll
  for (int g = 0; g < 3; ++g)
#pragma unroll
    for (int c = 0; c < 16; ++c)
      BGI[g][c] = cvt_frag(WI + (size_t)(g * H_ + urow) * H_ + 32 * c + quad * 8);
  float bi_[3], bh_[3];
#pragma unroll
  for (int g = 0; g < 3; ++g) { bi_[g] = bi[g * H_ + urow]; bh_[g] = bh[g * H_ + urow]; }
  float hp[4] = {0.f, 0.f, 0.f, 0.f};

  for (int s = 1; s <= 512; ++s) {
    poll_flags(fl, lane, s, INT_MIN);
    const unsigned short* Agi =
        ring + (size_t)(s & (RING - 1)) * B_ * H_ + (size_t)b * H_;
    f32x4 agi[3];
#pragma unroll
    for (int g = 0; g < 3; ++g) agi[g] = (f32x4){0.f, 0.f, 0.f, 0.f};
#pragma unroll
    for (int c = 0; c < 16; ++c) {
      bf16x8 a = load_bf8_coh(Agi + 32 * c + quad * 8);
      agi[0] = mfma16(a, BGI[0][c], agi[0]);
      agi[1] = mfma16(a, BGI[1][c], agi[1]);
      agi[2] = mfma16(a, BGI[2][c], agi[2]);
    }
    __syncthreads();   // partner published gh partials to LDS
    unsigned us[4];
#pragma unroll
    for (int r = 0; r < 4; ++r) {
      float g0 = exch[0][lane][r], g1 = exch[1][lane][r], g2 = exch[2][lane][r];
      float rr = sigm(agi[0][r] + bi_[0] + g0 + bh_[0]);
      float zz = sigm(agi[1][r] + bi_[1] + g1 + bh_[1]);
      float nn = tanh_(agi[2][r] + bi_[2] + rr * (g2 + bh_[2]));
      float hv = (1.f - zz) * nn + zz * hp[r];
      hp[r] = hv;
      us[r] = f2bf(hv);
    }
    unsigned* dst = (unsigned*)(ys + (size_t)(s - 1) * B_ * H_);
    store_h_packed(dst, m0, u0, quad, l16, us);
    __syncthreads();   // drains all waves' vmcnt (both consumers' stores acked)
    if (threadIdx.x == 0)
      __hip_atomic_store(fl + 32 + cblk, (unsigned)s, __ATOMIC_RELAXED,
                         __HIP_MEMORY_SCOPE_AGENT);
  }
}

// cell1 producer wave: step s: poll f1>=s-1; gh = h1(s-1)@Whh1 -> LDS.
__device__ __forceinline__ void cell1_prod(
    unsigned* fl, int lane, int u0, int m0,
    const unsigned short* __restrict__ ys,
    const float* __restrict__ WH, float (*exch)[64][4]) {
  const int quad = lane >> 4, l16 = lane & 15;
  const int b = m0 + l16, urow = u0 + l16;
  bf16x8 BGH[3][16];
#pragma unroll
  for (int g = 0; g < 3; ++g)
#pragma unroll
    for (int c = 0; c < 16; ++c)
      BGH[g][c] = cvt_frag(WH + (size_t)(g * H_ + urow) * H_ + 32 * c + quad * 8);

  for (int s = 1; s <= 512; ++s) {
    f32x4 agh[3];
#pragma unroll
    for (int g = 0; g < 3; ++g) agh[g] = (f32x4){0.f, 0.f, 0.f, 0.f};
    if (s >= 2) {
      poll_flags(fl, lane, INT_MIN, s - 1);
      const unsigned short* Agh = ys + (size_t)(s - 2) * B_ * H_ + (size_t)b * H_;
#pragma unroll
      for (int c = 0; c < 16; ++c) {
        bf16x8 a = load_bf8_coh(Agh + 32 * c + quad * 8);
        agh[0] = mfma16(a, BGH[0][c], agh[0]);
        agh[1] = mfma16(a, BGH[1][c], agh[1]);
        agh[2] = mfma16(a, BGH[2][c], agh[2]);
      }
    }
#pragma unroll
    for (int g = 0; g < 3; ++g)
#pragma unroll
      for (int r = 0; r < 4; ++r) exch[g][lane][r] = agh[g][r];
    __syncthreads();
    __syncthreads();
  }
}

__launch_bounds__(256, 1)
__global__ void rnn_kernel(const unsigned short* __restrict__ xn,
                           unsigned short* __restrict__ ys,
                           unsigned short* __restrict__ ring,
                           unsigned* __restrict__ flg,
                           const float* __restrict__ Wih0, const float* __restrict__ Whh0,
                           const float* __restrict__ bih0, const float* __restrict__ bhh0,
                           const float* __restrict__ Wih1, const float* __restrict__ Whh1,
                           const float* __restrict__ bih1, const float* __restrict__ bhh1) {
  __shared__ float exch[2][3][64][4];

  const int grp = blockIdx.x & 7;
  const int idx = blockIdx.x >> 3;       // 0..23
  unsigned* fl = flg + grp * 64;         // [0..31] f0 per-wave, [32..47] f1 per-block
  const int m0 = grp * 16;
  const int wave = threadIdx.x >> 6;
  const int lane = threadIdx.x & 63;

  if (idx < 8) {
    int wid = idx * 4 + wave;            // 0..31
    cell0_run(fl, wid, lane, wid * 16, m0, xn,
              ring, Wih0, Whh0, bih0, bhh0);
  } else {
    int c = idx - 8;                     // 0..15
    int sub = wave >> 1, wr = wave & 1;
    int u0 = (c * 2 + sub) * 16;
    if (wr == 0)
      cell1_cons(fl, c, lane, u0, m0, ys, ring, Wih1, bih1, bhh1, exch[sub]);
    else
      cell1_prod(fl, lane, u0, m0, ys, Whh1, exch[sub]);
  }
}

// ---------------------------------------------------------------------------
__global__ void out_kernel(const unsigned short* __restrict__ ys,
                           const float* __restrict__ Wout, const float* __restrict__ bout,
                           const float* __restrict__ w_o, const float* __restrict__ b_o,
                           const float* __restrict__ w_c, const float* __restrict__ b_c,
                           const float* __restrict__ stats,
                           float* __restrict__ dout) {
  int lane = threadIdx.x;
  int quad = lane >> 4, l16 = lane & 15;
  int nb = blockIdx.x % 5, mc = blockIdx.x / 5;
  int ch = nb * 16 + l16;

  bf16x8 BW[16];
#pragma unroll
  for (int c = 0; c < 16; ++c)
    BW[c] = cvt_frag(Wout + (size_t)ch * 512 + 32 * c + quad * 8);
  float bo = bout[ch];
  float rb, rw; const float* mm; const float* ss; int cs, cidx;
  if (ch < 16) { rb = b_o[ch]; rw = w_o[ch]; mm = stats + ST_OM; ss = stats + ST_OSD; cs = 16; cidx = ch; }
  else         { rb = b_c[ch - 16]; rw = w_c[ch - 16]; mm = stats + ST_CM; ss = stats + ST_CSD; cs = 64; cidx = ch - 16; }

  for (int i = 0; i < 8; ++i) {
    int mt = mc * 8 + i;
    const unsigned short* A = ys + (size_t)(mt * 16 + l16) * 512;
    f32x4 acc = {0.f, 0.f, 0.f, 0.f};
#pragma unroll
    for (int c = 0; c < 16; ++c)
      acc = mfma16(load_bf8(A + 32 * c + quad * 8), BW[c], acc);
#pragma unroll
    for (int r = 0; r < 4; ++r) {
      int rr = mt * 16 + quad * 4 + r;
      int t = rr >> 7;
      int b = rr & 127;
      float m = mm[b * cs + cidx], sd = ss[b * cs + cidx];
      float v = (acc[r] + bo - rb) / rw * (sd + EPSR) + m;
      size_t off = (ch < 16)
          ? ((size_t)b * 8192 + (size_t)t * 16 + ch)
          : ((size_t)1048576 + (size_t)b * 32768 + (size_t)t * 64 + (ch - 16));
      dout[off] = v;
    }
  }
}

// ---------------------------------------------------------------------------
extern "C" void kernel_launch(void* const* d_in, const int* in_sizes, int n_in,
                              void* d_out, int out_size, void* d_ws, size_t ws_size,
                              hipStream_t stream) {
  const float* cov  = (const float*)d_in[0];
  const float* trt  = (const float*)d_in[1];
  const float* outh = (const float*)d_in[2];
  const float* Wih0 = (const float*)d_in[3];
  const float* Whh0 = (const float*)d_in[4];
  const float* bih0 = (const float*)d_in[5];
  const float* bhh0 = (const float*)d_in[6];
  const float* Wih1 = (const float*)d_in[7];
  const float* Whh1 = (const float*)d_in[8];
  const float* bih1 = (const float*)d_in[9];
  const float* bhh1 = (const float*)d_in[10];
  const float* Wout = (const float*)d_in[11];
  const float* bout = (const float*)d_in[12];
  const float* w_t  = (const float*)d_in[13];
  const float* b_t  = (const float*)d_in[14];
  const float* w_o  = (const float*)d_in[15];
  const float* b_o  = (const float*)d_in[16];
  const float* w_c  = (const float*)d_in[17];
  const float* b_c  = (const float*)d_in[18];

  char* ws = (char*)d_ws;
  unsigned short* xn = (unsigned short*)(ws + XN_OFF);
  unsigned short* ys = (unsigned short*)(ws + YS_OFF);
  unsigned short* ring = (unsigned short*)(ws + RING_OFF);
  unsigned* flg = (unsigned*)(ws + FLG_OFF);
  float* stats = (float*)(ws + ST_OFF);

  // ws re-poisoned 0xAA each call: zero ring slot 0 (h0(0)=0) and flags.
  hipMemsetAsync((void*)(ws + RING_OFF), 0, SLOT_BYTES, stream);
  hipMemsetAsync((void*)(ws + FLG_OFF), 0, FLG_BYTES, stream);

  stats_kernel<<<128, 128, 0, stream>>>(trt, outh, cov, stats);
  norm_kernel<<<(L_ * B_ * CI_) / 256, 256, 0, stream>>>(
      trt, outh, cov, stats, w_t, b_t, w_o, b_o, w_c, b_c, xn);

  rnn_kernel<<<192, 256, 0, stream>>>(xn, ys, ring, flg,
                                      Wih0, Whh0, bih0, bhh0,
                                      Wih1, Whh1, bih1, bhh1);

  out_kernel<<<2560, 64, 0, stream>>>(ys, Wout, bout, w_o, b_o, w_c, b_c,
                                      stats, (float*)d_out);
}